// Round 1
// baseline (363.809 us; speedup 1.0000x reference)
//
#include <hip/hip_runtime.h>

#define DT 0.03f
#define SEQ_LEN 30
#define D_STEER (0.4f * 0.03f)

__global__ __launch_bounds__(256) void ccdec_kernel(
    const float* __restrict__ z,
    const float* __restrict__ init_state,
    float* __restrict__ out,
    int B)
{
    int b = blockIdx.x * blockDim.x + threadIdx.x;
    if (b >= B) return;

    // ---- loads (coalesced-ish vector loads) ----
    float2 zv  = *reinterpret_cast<const float2*>(z + 2ull * (size_t)b);
    const float* st = init_state + 6ull * (size_t)b;   // 24B stride, 8B aligned
    float2 s01 = *reinterpret_cast<const float2*>(st + 0);
    float2 s23 = *reinterpret_cast<const float2*>(st + 2);
    float2 s45 = *reinterpret_cast<const float2*>(st + 4);

    float x   = s01.x;
    float y   = s01.y;
    float psi = s23.x;
    float v   = s23.y;
    float last_st = s45.y;   // init_state[:,5]

    // ---- steering / pedal preamble (mirror clip_by_tensor semantics) ----
    float steering = zv.y * 0.5f;
    float tmin = last_st - D_STEER;
    float tmax = last_st + D_STEER;
    // r = (t>tmin)*t + (t<tmin)*tmin   (equality -> 0, literal semantics)
    float r = (steering > tmin) ? steering : ((steering < tmin) ? tmin : 0.0f);
    // r = (r<=tmax)*r + (r>tmax)*tmax
    r = (r <= tmax) ? r : tmax;
    steering = fminf(fmaxf(r, -0.5f), 0.5f);

    float pedal = zv.x * 2.5f;
    float beta  = fminf(fmaxf(steering, -0.5f), 0.5f);
    float a_t   = fminf(fmaxf(pedal, -2.5f), 2.5f);
    float tan_beta = __tanf(beta);
    float dpsi_k   = tan_beta * (1.0f / 2.5f) * DT;  // psi += v * dpsi_k
    float adt      = a_t * DT;

    float4* outp = reinterpret_cast<float4*>(out + 120ull * (size_t)b);

    #pragma unroll
    for (int t = 0; t < SEQ_LEN; ++t) {
        float v1 = fminf(fmaxf(v + adt, 0.0f), 10.0f);
        psi = v * dpsi_k + psi;          // uses OLD v
        float s, c;
        __sincosf(psi, &s, &c);
        x = v1 * c * DT + x;
        y = v1 * s * DT + y;
        v = v1;
        outp[t] = make_float4(x, y, psi, v);
    }
}

extern "C" void kernel_launch(void* const* d_in, const int* in_sizes, int n_in,
                              void* d_out, int out_size, void* d_ws, size_t ws_size,
                              hipStream_t stream)
{
    const float* z          = (const float*)d_in[0];   // (B, 2) f32
    const float* init_state = (const float*)d_in[1];   // (B, 6) f32
    float* out = (float*)d_out;                        // (B, 30, 4) f32

    int B = in_sizes[0] / 2;
    int blocks = (B + 255) / 256;
    ccdec_kernel<<<blocks, 256, 0, stream>>>(z, init_state, out, B);
}